// Round 1
// baseline (149.100 us; speedup 1.0000x reference)
//
#include <hip/hip_runtime.h>

#define EPS 1e-7f
#define BATCH 8
#define NPT 2048   // points per batch
#define NFEAT 6

// ws layout (floats): pow[BATCH*NPT] | dmin[BATCH] | inv_sqrad | beta_eff
#define WS_POW   0
#define WS_DMIN  (BATCH * NPT)
#define WS_ISR   (BATCH * NPT + BATCH)
#define WS_BEFF  (BATCH * NPT + BATCH + 1)

__global__ __launch_bounds__(256)
void precompute_kernel(const float* __restrict__ emb,
                       const float* __restrict__ alpha,
                       const float* __restrict__ beta,
                       const float* __restrict__ radius,
                       float* __restrict__ ws) {
    int b = blockIdx.x;
    int tid = threadIdx.x;
    float a2 = 2.0f * alpha[0];
    const float* mom = emb + (size_t)b * NFEAT * NPT + 4 * NPT;
    float* powp = ws + WS_POW + (size_t)b * NPT;

    float local_min = 3.0e38f;
    for (int n = tid; n < NPT; n += 256) {
        float m = mom[n];
        float p = __expf(a2 * __logf(m));   // momentum^(2*alpha)
        powp[n] = p;
        local_min = fminf(local_min, p);
    }
    // wave (64-lane) shuffle reduce, then LDS across 4 waves
    for (int off = 32; off > 0; off >>= 1)
        local_min = fminf(local_min, __shfl_down(local_min, off, 64));
    __shared__ float smin[4];
    int wave = tid >> 6;
    if ((tid & 63) == 0) smin[wave] = local_min;
    __syncthreads();
    if (tid == 0) {
        float m = fminf(fminf(smin[0], smin[1]), fminf(smin[2], smin[3]));
        ws[WS_DMIN + b] = m + EPS;
    }
    if (b == 0 && tid == 0) {
        float r = radius[0];
        ws[WS_ISR] = 1.0f / (r * r + EPS);
        float bt = beta[0];
        ws[WS_BEFF] = bt * bt * 1e-4f;   // beta^2 / 10000
    }
}

// One block per output row (b, n); 512 threads x float4 = 2048 columns.
__global__ __launch_bounds__(512)
void wij_kernel(const float* __restrict__ emb,
                const float* __restrict__ ws,
                float* __restrict__ out) {
    int row = blockIdx.x;              // 0 .. BATCH*NPT-1
    int b = row >> 11;                 // / NPT
    int n = row & (NPT - 1);

    const float* base = emb + (size_t)b * NFEAT * NPT;
    float xn = base[1 * NPT + n];
    float yn = base[2 * NPT + n];
    const float* powp = ws + WS_POW + (size_t)b * NPT;
    float pn   = powp[n];
    float dmin = ws[WS_DMIN + b];
    float isr  = ws[WS_ISR];
    float beff = ws[WS_BEFF];
    // w = exp(-beff*(d_alpha - dmin)/dmin) = exp(beff - (beff/dmin)*d_alpha)
    float c = beff / dmin;
    float cisr = c * isr;              // fold 1/sqradius into the coefficient

    int t = threadIdx.x;
    float4 cx = ((const float4*)(base + 1 * NPT))[t];
    float4 cy = ((const float4*)(base + 2 * NPT))[t];
    float4 pw = ((const float4*)powp)[t];

    float4 w;
    {
        float dx = xn - cx.x, dy = yn - cy.x;
        float da = (dx * dx + dy * dy) * fminf(pn, pw.x);
        w.x = __expf(beff - cisr * da);
    }
    {
        float dx = xn - cx.y, dy = yn - cy.y;
        float da = (dx * dx + dy * dy) * fminf(pn, pw.y);
        w.y = __expf(beff - cisr * da);
    }
    {
        float dx = xn - cx.z, dy = yn - cy.z;
        float da = (dx * dx + dy * dy) * fminf(pn, pw.z);
        w.z = __expf(beff - cisr * da);
    }
    {
        float dx = xn - cx.w, dy = yn - cy.w;
        float da = (dx * dx + dy * dy) * fminf(pn, pw.w);
        w.w = __expf(beff - cisr * da);
    }

    float* outrow = out + (size_t)row * NPT;
    ((float4*)outrow)[t] = w;
}

extern "C" void kernel_launch(void* const* d_in, const int* in_sizes, int n_in,
                              void* d_out, int out_size, void* d_ws, size_t ws_size,
                              hipStream_t stream) {
    const float* emb    = (const float*)d_in[0];
    const float* alpha  = (const float*)d_in[1];
    const float* beta   = (const float*)d_in[2];
    const float* radius = (const float*)d_in[3];
    float* out = (float*)d_out;
    float* ws  = (float*)d_ws;

    precompute_kernel<<<BATCH, 256, 0, stream>>>(emb, alpha, beta, radius, ws);
    wij_kernel<<<BATCH * NPT, 512, 0, stream>>>(emb, ws, out);
}